// Round 3
// baseline (775.420 us; speedup 1.0000x reference)
//
#include <hip/hip_runtime.h>
#include <stdint.h>

#define T_MASK 4194303u          // T = 2^22
#define PI2_C  2654435761u
#define NBKT   16384             // 128x128 Morton buckets

__constant__ float c_NL[16] = {
    16.f, 20.f, 25.f, 32.f, 40.f, 50.f, 64.f, 80.f,
    101.f, 128.f, 161.f, 203.f, 256.f, 322.f, 406.f, 512.f
};

__device__ __forceinline__ uint32_t part1by1(uint32_t v) {
    v &= 0xffu;
    v = (v | (v << 4)) & 0x0F0Fu;
    v = (v | (v << 2)) & 0x3333u;
    v = (v | (v << 1)) & 0x5555u;
    return v;
}

__global__ __launch_bounds__(256) void zero_counts(uint32_t* counts) {
    int i = blockIdx.x * 256 + threadIdx.x;
    if (i < NBKT) counts[i] = 0;
}

__global__ __launch_bounds__(256) void hist_kernel(
    const float* __restrict__ x, uint32_t* __restrict__ keys,
    uint32_t* __restrict__ counts, int npts)
{
    int i = blockIdx.x * 256 + threadIdx.x;
    if (i >= npts) return;
    float px = x[2 * i], py = x[2 * i + 1];
    int cx = (int)(px * 128.f); cx = cx < 0 ? 0 : (cx > 127 ? 127 : cx);
    int cy = (int)(py * 128.f); cy = cy < 0 ? 0 : (cy > 127 ? 127 : cy);
    uint32_t key = part1by1((uint32_t)cx) | (part1by1((uint32_t)cy) << 1);
    keys[i] = key;
    atomicAdd(&counts[key], 1u);
}

// single block, 1024 threads: in-place exclusive prefix scan of counts[NBKT]
__global__ __launch_bounds__(1024) void scan_kernel(uint32_t* __restrict__ counts) {
    __shared__ uint32_t sums[1024];
    int t = threadIdx.x;
    uint32_t local[NBKT / 1024];
    uint32_t s = 0;
    #pragma unroll
    for (int i = 0; i < NBKT / 1024; ++i) {
        local[i] = counts[t * (NBKT / 1024) + i];
        s += local[i];
    }
    sums[t] = s;
    __syncthreads();
    for (int off = 1; off < 1024; off <<= 1) {
        uint32_t v = (t >= off) ? sums[t - off] : 0u;
        __syncthreads();
        sums[t] += v;
        __syncthreads();
    }
    uint32_t run = (t > 0) ? sums[t - 1] : 0u;
    #pragma unroll
    for (int i = 0; i < NBKT / 1024; ++i) {
        uint32_t c = local[i];
        counts[t * (NBKT / 1024) + i] = run;
        run += c;
    }
}

__global__ __launch_bounds__(256) void scatter_kernel(
    const uint32_t* __restrict__ keys, uint32_t* __restrict__ offsets,
    uint32_t* __restrict__ order, int npts)
{
    int i = blockIdx.x * 256 + threadIdx.x;
    if (i >= npts) return;
    uint32_t pos = atomicAdd(&offsets[keys[i]], 1u);
    order[pos] = (uint32_t)i;
}

// One thread = one POINT, looping over all 16 levels.
// - wave = 64 spatially-consecutive (sorted) points; at each level the wave's
//   gather footprint is identical to the old per-(point,level) kernel.
// - per-wave rotated level start keeps instantaneous level footprints mixed
//   across the machine (same decorrelation the old diagonal rotation gave).
// - the full 128B output row is written by ONE thread -> no cross-XCD L2
//   line sharing / write amplification on `out`.
__global__ __launch_bounds__(256) void enc_cubic_pp_kernel(
    const float* __restrict__ x,
    const float* __restrict__ ht,
    const uint32_t* __restrict__ order,
    float* __restrict__ out,
    int npts)
{
    uint32_t bid = blockIdx.x;
    uint32_t nb = gridDim.x;
    if ((nb & 7u) == 0u) {                 // XCD-aware swizzle (bijective: nb%8==0)
        uint32_t chunk = nb >> 3;
        bid = (bid & 7u) * chunk + (bid >> 3);
    }
    uint32_t r = bid * 256u + threadIdx.x; // sorted rank
    if (r >= (uint32_t)npts) return;
    int n = (int)order[r];
    float2 pxy = *(const float2*)(x + 2u * (size_t)n);
    float px = pxy.x;
    float py = pxy.y;
    float* orow = out + (size_t)n * 32u;
    uint32_t lrot = (r >> 6) & 15u;        // per-wave level rotation

    #pragma unroll 1
    for (int k = 0; k < 16; ++k) {
        uint32_t l = ((uint32_t)k + lrot) & 15u;   // uniform across the wave
        float NL = c_NL[l];
        float xs = px * NL;
        float ys = py * NL;
        int ix = (int)xs;
        int iy = (int)ys;
        float tx = xs - (float)ix;
        float ty = ys - (float)iy;

        float tx2 = tx * tx, tx3 = tx2 * tx;
        float ty2 = ty * ty, ty3 = ty2 * ty;
        float wxa[4], wya[4];
        wxa[0] = -0.5f * tx + tx2 - 0.5f * tx3;
        wxa[1] = 1.0f - 2.5f * tx2 + 1.5f * tx3;
        wxa[2] = 0.5f * tx + 2.0f * tx2 - 1.5f * tx3;
        wxa[3] = -0.5f * tx2 + 0.5f * tx3;
        wya[0] = -0.5f * ty + ty2 - 0.5f * ty3;
        wya[1] = 1.0f - 2.5f * ty2 + 1.5f * ty3;
        wya[2] = 0.5f * ty + 2.0f * ty2 - 1.5f * ty3;
        wya[3] = -0.5f * ty2 + 0.5f * ty3;

        const float* base = ht + l;
        float acc0 = 0.f, acc1 = 0.f;
        #pragma unroll
        for (int j = 0; j < 4; ++j) {
            uint32_t hy = (uint32_t)(iy + j) * PI2_C;
            float r0 = 0.f, r1 = 0.f;
            #pragma unroll
            for (int i = 0; i < 4; ++i) {
                uint32_t h = (((uint32_t)(ix + i)) ^ hy) & T_MASK;
                const float* p = base + (size_t)h * 32u;
                r0 += wxa[i] * p[0];
                r1 += wxa[i] * p[16];
            }
            acc0 += wya[j] * r0;
            acc1 += wya[j] * r1;
        }
        *(float2*)(orow + 2u * l) = make_float2(acc0, acc1);
    }
}

extern "C" void kernel_launch(void* const* d_in, const int* in_sizes, int n_in,
                              void* d_out, int out_size, void* d_ws, size_t ws_size,
                              hipStream_t stream) {
    const float* x  = (const float*)d_in[0];
    const float* ht = (const float*)d_in[1];
    float* out = (float*)d_out;
    int npts = in_sizes[0] / 2;

    // workspace layout: counts[NBKT] | keys[npts] | order[npts]
    uint32_t* counts = (uint32_t*)d_ws;
    uint32_t* keys   = counts + NBKT;
    uint32_t* order  = keys + npts;

    int pb = (npts + 255) / 256;
    zero_counts<<<(NBKT + 255) / 256, 256, 0, stream>>>(counts);
    hist_kernel<<<pb, 256, 0, stream>>>(x, keys, counts, npts);
    scan_kernel<<<1, 1024, 0, stream>>>(counts);
    scatter_kernel<<<pb, 256, 0, stream>>>(keys, counts, order, npts);

    enc_cubic_pp_kernel<<<pb, 256, 0, stream>>>(x, ht, order, out, npts);
}